// Round 1
// baseline (204.122 us; speedup 1.0000x reference)
//
#include <hip/hip_runtime.h>
#include <hip/hip_bf16.h>

typedef short v8s __attribute__((ext_vector_type(8)));
typedef float v4f __attribute__((ext_vector_type(4)));

#define MFMA16(a, b, c) __builtin_amdgcn_mfma_f32_16x16x32_bf16((a), (b), (c), 0, 0, 0)

constexpr int Bsz   = 128;
constexpr int Lq    = 32;
constexpr int Ld    = 512;
constexpr int H     = 768;
constexpr int D     = 128;
constexpr int QROWS = Bsz * Lq;          // 4096
constexpr int DROWS = Bsz * Ld;          // 65536
constexpr int MTOT  = QROWS + 2 * DROWS; // 135168
static_assert(MTOT % 32 == 0, "rows divisible by 32");

// f32 -> bf16 bits, round-to-nearest-even (inputs are finite; no NaN path needed)
static __device__ __forceinline__ unsigned short f2b(float f) {
    unsigned int u = __builtin_bit_cast(unsigned int, f);
    unsigned int r = u + 0x7FFFu + ((u >> 16) & 1u);
    return (unsigned short)(r >> 16);
}

// ---------------------------------------------------------------------------
// Kernel 1: Wt[d][h] = bf16(W[h][d])   (so B-fragments are contiguous 16B)
// ---------------------------------------------------------------------------
__global__ void prep_w_kernel(const float* __restrict__ W,
                              unsigned short* __restrict__ Wt) {
    int idx = blockIdx.x * 256 + threadIdx.x;
    if (idx < H * D) {
        int d = idx / H, h = idx % H;
        Wt[idx] = f2b(W[h * D + d]);
    }
}

// ---------------------------------------------------------------------------
// Kernel 2: project 32 rows per wave (1 wave per block), bias, L2-norm, mask,
//           write normalized bf16 embeddings. No LDS; register double-buffer.
// ---------------------------------------------------------------------------
struct Frag {
    float4 fa[4]; // A raw f32: rows (m=0,m=1) x 8 floats
    v8s    wb[8]; // B bf16 fragments for 8 N-tiles
};

__global__ __launch_bounds__(64) void proj_norm_kernel(
    const float* __restrict__ qh, const float* __restrict__ pdh,
    const float* __restrict__ ndh, const float* __restrict__ bias,
    const int* __restrict__ pdm, const int* __restrict__ ndm,
    const unsigned short* __restrict__ Wt, unsigned short* __restrict__ emb)
{
    const int lane = threadIdx.x & 63;
    const int l15  = lane & 15, lg = lane >> 4;
    const long row0 = (long)blockIdx.x * 32;

    const float* src; const int* mask; long srow;
    if (row0 < QROWS)              { src = qh;  srow = row0;                 mask = nullptr; }
    else if (row0 < QROWS + DROWS) { src = pdh; srow = row0 - QROWS;         mask = pdm; }
    else                           { src = ndh; srow = row0 - QROWS - DROWS; mask = ndm; }

    float bv[8];
#pragma unroll
    for (int n = 0; n < 8; ++n) bv[n] = bias[n * 16 + l15];

    const float* a0p = src + (srow + l15) * (long)H + lg * 8;
    const float* a1p = a0p + (long)16 * H;
    const unsigned short* wp = Wt + (size_t)l15 * H + lg * 8;

    v4f acc[2][8];
#pragma unroll
    for (int m = 0; m < 2; ++m)
#pragma unroll
        for (int n = 0; n < 8; ++n) acc[m][n] = (v4f){0.f, 0.f, 0.f, 0.f};

    auto load_frag = [&](int kk, Frag& f) {
        const float* p0 = a0p + kk * 32;
        const float* p1 = a1p + kk * 32;
        f.fa[0] = *(const float4*)(p0);
        f.fa[1] = *(const float4*)(p0 + 4);
        f.fa[2] = *(const float4*)(p1);
        f.fa[3] = *(const float4*)(p1 + 4);
#pragma unroll
        for (int n = 0; n < 8; ++n)
            f.wb[n] = *(const v8s*)(wp + (size_t)n * 16 * H + kk * 32);
    };

    auto do_mfma = [&](Frag& f) {
        v8s a0, a1;
        a0[0] = (short)f2b(f.fa[0].x); a0[1] = (short)f2b(f.fa[0].y);
        a0[2] = (short)f2b(f.fa[0].z); a0[3] = (short)f2b(f.fa[0].w);
        a0[4] = (short)f2b(f.fa[1].x); a0[5] = (short)f2b(f.fa[1].y);
        a0[6] = (short)f2b(f.fa[1].z); a0[7] = (short)f2b(f.fa[1].w);
        a1[0] = (short)f2b(f.fa[2].x); a1[1] = (short)f2b(f.fa[2].y);
        a1[2] = (short)f2b(f.fa[2].z); a1[3] = (short)f2b(f.fa[2].w);
        a1[4] = (short)f2b(f.fa[3].x); a1[5] = (short)f2b(f.fa[3].y);
        a1[6] = (short)f2b(f.fa[3].z); a1[7] = (short)f2b(f.fa[3].w);
#pragma unroll
        for (int n = 0; n < 8; ++n) {
            acc[0][n] = MFMA16(a0, f.wb[n], acc[0][n]);
            acc[1][n] = MFMA16(a1, f.wb[n], acc[1][n]);
        }
    };

    Frag fX, fY;
    load_frag(0, fX);
#pragma unroll 1
    for (int kk = 0; kk < 22; kk += 2) {
        load_frag(kk + 1, fY);
        do_mfma(fX);
        load_frag(kk + 2, fX);
        do_mfma(fY);
    }
    load_frag(23, fY);
    do_mfma(fX);
    do_mfma(fY);

    // epilogue: bias, sum-of-squares across the 16 lanes holding each row,
    // rsqrt scale (0 if masked), store bf16
#pragma unroll
    for (int m = 0; m < 2; ++m) {
        float ss[4] = {0.f, 0.f, 0.f, 0.f};
#pragma unroll
        for (int n = 0; n < 8; ++n) {
            v4f v = acc[m][n];
            v[0] += bv[n]; v[1] += bv[n]; v[2] += bv[n]; v[3] += bv[n];
            acc[m][n] = v;
            ss[0] += v[0] * v[0]; ss[1] += v[1] * v[1];
            ss[2] += v[2] * v[2]; ss[3] += v[3] * v[3];
        }
#pragma unroll
        for (int off = 1; off < 16; off <<= 1) {
            ss[0] += __shfl_xor(ss[0], off);
            ss[1] += __shfl_xor(ss[1], off);
            ss[2] += __shfl_xor(ss[2], off);
            ss[3] += __shfl_xor(ss[3], off);
        }
        float sc[4];
#pragma unroll
        for (int r = 0; r < 4; ++r) {
            float s = 1.0f / fmaxf(sqrtf(ss[r]), 1e-12f);
            if (mask) s *= (float)mask[srow + m * 16 + lg * 4 + r];
            sc[r] = s;
        }
        unsigned short* op = emb + (size_t)(row0 + m * 16 + lg * 4) * D + l15;
#pragma unroll
        for (int n = 0; n < 8; ++n)
#pragma unroll
            for (int r = 0; r < 4; ++r)
                op[(size_t)r * D + n * 16] = f2b(acc[m][n][r] * sc[r]);
    }
}

// ---------------------------------------------------------------------------
// Kernel 3: MaxSim. One block per (batch, side); 4 waves x 128 doc tokens.
// scores = Q[32x128] . Dtok[*x128]^T via MFMA, max over tokens, sum over q.
// ---------------------------------------------------------------------------
__global__ __launch_bounds__(256) void maxsim_kernel(
    const unsigned short* __restrict__ emb, float* __restrict__ out)
{
    const int blk  = blockIdx.x;       // 0..255
    const int b    = blk >> 1, side = blk & 1;
    const int wave = threadIdx.x >> 6, lane = threadIdx.x & 63;
    const int l15  = lane & 15, lg = lane >> 4;

    const unsigned short* Q  = emb + (size_t)(b * Lq) * D;
    const unsigned short* Dm = emb + (size_t)(QROWS + side * DROWS + b * Ld) * D;

    v4f acc[2][8];
#pragma unroll
    for (int m = 0; m < 2; ++m)
#pragma unroll
        for (int n = 0; n < 8; ++n) acc[m][n] = (v4f){0.f, 0.f, 0.f, 0.f};

    const int tok0 = wave * 128;
#pragma unroll
    for (int kk = 0; kk < 4; ++kk) {
        const int k0 = kk * 32 + lg * 8;
        v8s qa0 = *(const v8s*)(Q + (size_t)(l15) * D + k0);
        v8s qa1 = *(const v8s*)(Q + (size_t)(16 + l15) * D + k0);
#pragma unroll
        for (int n = 0; n < 8; ++n) {
            v8s db = *(const v8s*)(Dm + (size_t)(tok0 + n * 16 + l15) * D + k0);
            acc[0][n] = MFMA16(qa0, db, acc[0][n]);
            acc[1][n] = MFMA16(qa1, db, acc[1][n]);
        }
    }

    // per-q max over this wave's 128 tokens
    float mx[2][4];
#pragma unroll
    for (int m = 0; m < 2; ++m)
#pragma unroll
        for (int r = 0; r < 4; ++r) {
            float v = acc[m][0][r];
#pragma unroll
            for (int n = 1; n < 8; ++n) v = fmaxf(v, acc[m][n][r]);
            mx[m][r] = v;
        }
#pragma unroll
    for (int off = 1; off < 16; off <<= 1) {
#pragma unroll
        for (int m = 0; m < 2; ++m)
#pragma unroll
            for (int r = 0; r < 4; ++r)
                mx[m][r] = fmaxf(mx[m][r], __shfl_xor(mx[m][r], off));
    }

    __shared__ float red[4][32];
    if (l15 == 0) {
#pragma unroll
        for (int m = 0; m < 2; ++m)
#pragma unroll
            for (int r = 0; r < 4; ++r)
                red[wave][m * 16 + lg * 4 + r] = mx[m][r];
    }
    __syncthreads();

    if (threadIdx.x < 32) {
        int q = threadIdx.x;
        float v = fmaxf(fmaxf(red[0][q], red[1][q]), fmaxf(red[2][q], red[3][q]));
#pragma unroll
        for (int off = 1; off < 32; off <<= 1) v += __shfl_xor(v, off);
        if (q == 0) out[blk] = v;
    }
}

// ---------------------------------------------------------------------------
extern "C" void kernel_launch(void* const* d_in, const int* in_sizes, int n_in,
                              void* d_out, int out_size, void* d_ws, size_t ws_size,
                              hipStream_t stream)
{
    const float* qh   = (const float*)d_in[0];
    const float* pdh  = (const float*)d_in[1];
    const float* ndh  = (const float*)d_in[2];
    const float* W    = (const float*)d_in[3];
    const float* bias = (const float*)d_in[4];
    const int*   pdm  = (const int*)d_in[5];
    const int*   ndm  = (const int*)d_in[6];
    float* out = (float*)d_out;

    // workspace layout: Wt bf16 [D][H] (192KB), then emb bf16 [MTOT][D] (~34.6MB)
    unsigned short* Wt  = (unsigned short*)d_ws;
    unsigned short* emb = Wt + (size_t)H * D;

    prep_w_kernel<<<(H * D + 255) / 256, 256, 0, stream>>>(W, Wt);
    proj_norm_kernel<<<MTOT / 32, 64, 0, stream>>>(qh, pdh, ndh, bias, pdm, ndm, Wt, emb);
    maxsim_kernel<<<Bsz * 2, 256, 0, stream>>>(emb, out);
}